// Round 7
// baseline (38.569 us; speedup 1.0000x reference)
//
#include <hip/hip_runtime.h>

#define BB 32
#define TT 1024
#define T_OUT 4096
#define DD 384
#define F4_PER_ROW (DD / 4)            // 96
#define FRAMES_PER_BLOCK 64
#define BLOCKS_PER_BATCH (T_OUT / FRAMES_PER_BLOCK)   // 64
#define G_ITERS (FRAMES_PER_BLOCK * F4_PER_ROW / 256) // 24

typedef float f4 __attribute__((ext_vector_type(4)));

// Fused length-regulator: each block owns 64 consecutive output frames of one
// batch (96 KB of output). It recomputes the batch's masked-duration cumsum
// (4 KB row, L2-hot), scatters source-token indices for its frame window into
// an LDS map (pad frames stay -1), then streams the gather-copy.
// FRAMES sweep: 32 -> 35.4us, 128 -> 36.6us; probing 64.
__global__ __launch_bounds__(256) void lenreg_fused_kernel(
    const f4* __restrict__ xs,
    const int* __restrict__ durations,
    const int* __restrict__ input_lengths,
    f4* __restrict__ out) {
  const unsigned blk = blockIdx.x;
  const unsigned b = blk / BLOCKS_PER_BATCH;                       // batch
  const unsigned f0 = (blk % BLOCKS_PER_BATCH) * FRAMES_PER_BLOCK; // first frame
  const int tid = threadIdx.x;
  const int len = input_lengths[b];
  const int t0 = tid * 4;

  __shared__ int wred[4];
  __shared__ int wsum[4];
  __shared__ int map[FRAMES_PER_BLOCK];

  if (tid < FRAMES_PER_BLOCK) map[tid] = -1;  // pad marker

  // Load 4 durations per thread, mask past len.
  const int4 dv = *reinterpret_cast<const int4*>(&durations[b * TT + t0]);
  int d[4] = {dv.x, dv.y, dv.z, dv.w};
#pragma unroll
  for (int i = 0; i < 4; ++i)
    if (t0 + i >= len) d[i] = 0;

  int s = d[0] + d[1] + d[2] + d[3];

  // Block-wide total (need it before scan for the total==0 fallback).
  const int lane = tid & 63;
  const int wid = tid >> 6;
  int r = s;
#pragma unroll
  for (int off = 32; off > 0; off >>= 1) r += __shfl_xor(r, off);
  if (lane == 0) wred[wid] = r;
  __syncthreads();
  const int total = wred[0] + wred[1] + wred[2] + wred[3];

  // Reference fallback: if all masked durations are zero, d = valid (1s).
  if (total == 0) {
#pragma unroll
    for (int i = 0; i < 4; ++i) d[i] = (t0 + i < len) ? 1 : 0;
    s = d[0] + d[1] + d[2] + d[3];
  }

  // Inclusive wave scan of per-thread sums, then cross-wave offset.
  int v = s;
#pragma unroll
  for (int off = 1; off < 64; off <<= 1) {
    int u = __shfl_up(v, off);
    if (lane >= off) v += u;
  }
  if (lane == 63) wsum[wid] = v;
  __syncthreads();
  int wpre = 0;
#pragma unroll
  for (int w = 0; w < 4; ++w)
    if (w < wid) wpre += wsum[w];
  int run = wpre + v - s;  // exclusive prefix over this thread's 4 tokens

  // Scatter: token t owns frames [run, run + d[i]); intersect with window.
  const int flo = (int)f0, fhi = (int)f0 + FRAMES_PER_BLOCK;
#pragma unroll
  for (int i = 0; i < 4; ++i) {
    int lo = run, hi = run + d[i];
    run = hi;
    lo = lo < flo ? flo : lo;
    hi = hi > fhi ? fhi : hi;
    for (int k = lo; k < hi; ++k) map[k - flo] = t0 + i;
  }
  __syncthreads();

  // Streaming gather: 64 frames x 96 f4 = 6144 f4 = 256 threads x 24 iters.
  const f4* xrow = xs + (size_t)b * TT * F4_PER_ROW;
  f4* obase = out + ((size_t)b * T_OUT + f0) * F4_PER_ROW;
#pragma unroll 12
  for (int it = 0; it < G_ITERS; ++it) {
    const unsigned o = (unsigned)it * 256u + (unsigned)tid;
    const unsigned fl = o / F4_PER_ROW;          // frame within window
    const unsigned ln = o - fl * F4_PER_ROW;     // f4 within row
    const int src = map[fl];
    f4 val = {0.f, 0.f, 0.f, 0.f};
    if (src >= 0) val = xrow[(unsigned)src * F4_PER_ROW + ln];
    obase[o] = val;
  }
}

extern "C" void kernel_launch(void* const* d_in, const int* in_sizes, int n_in,
                              void* d_out, int out_size, void* d_ws, size_t ws_size,
                              hipStream_t stream) {
  const float* xs = (const float*)d_in[0];
  const int* durations = (const int*)d_in[1];
  const int* input_lengths = (const int*)d_in[2];
  float* out = (float*)d_out;

  lenreg_fused_kernel<<<BB * BLOCKS_PER_BATCH, 256, 0, stream>>>(
      (const f4*)xs, durations, input_lengths, (f4*)out);
}

// Round 8
// 35.192 us; speedup vs baseline: 1.0960x; 1.0960x over previous
//
#include <hip/hip_runtime.h>

#define BB 32
#define TT 1024
#define T_OUT 4096
#define DD 384
#define F4_PER_ROW (DD / 4)            // 96
#define FRAMES_PER_BLOCK 32
#define BLOCKS_PER_BATCH (T_OUT / FRAMES_PER_BLOCK)   // 128
#define G_ITERS (FRAMES_PER_BLOCK * F4_PER_ROW / 256) // 12

typedef float f4 __attribute__((ext_vector_type(4)));

// Fused length-regulator: each block owns 32 consecutive output frames of one
// batch. It recomputes the batch's masked-duration cumsum (4 KB row, L2-hot,
// shared by 128 blocks), scatters source-token indices for its frame window
// into an LDS map (pad frames stay -1), then does the streaming gather-copy.
// FRAMES sweep: 32 -> 35.4us (best), 64 -> 38.6us, 128 -> 36.6us (noise-flat;
// 32 keeps 4096 blocks = 16 blocks/CU oversubscription to hide the prologue).
__global__ __launch_bounds__(256) void lenreg_fused_kernel(
    const f4* __restrict__ xs,
    const int* __restrict__ durations,
    const int* __restrict__ input_lengths,
    f4* __restrict__ out) {
  const unsigned blk = blockIdx.x;
  const unsigned b = blk / BLOCKS_PER_BATCH;                    // batch
  const unsigned f0 = (blk % BLOCKS_PER_BATCH) * FRAMES_PER_BLOCK; // first frame
  const int tid = threadIdx.x;
  const int len = input_lengths[b];
  const int t0 = tid * 4;

  __shared__ int wred[4];
  __shared__ int wsum[4];
  __shared__ int map[FRAMES_PER_BLOCK];

  if (tid < FRAMES_PER_BLOCK) map[tid] = -1;  // pad marker

  // Load 4 durations per thread, mask past len.
  const int4 dv = *reinterpret_cast<const int4*>(&durations[b * TT + t0]);
  int d[4] = {dv.x, dv.y, dv.z, dv.w};
#pragma unroll
  for (int i = 0; i < 4; ++i)
    if (t0 + i >= len) d[i] = 0;

  int s = d[0] + d[1] + d[2] + d[3];

  // Block-wide total (need it before scan for the total==0 fallback).
  const int lane = tid & 63;
  const int wid = tid >> 6;
  int r = s;
#pragma unroll
  for (int off = 32; off > 0; off >>= 1) r += __shfl_xor(r, off);
  if (lane == 0) wred[wid] = r;
  __syncthreads();
  const int total = wred[0] + wred[1] + wred[2] + wred[3];

  // Reference fallback: if all masked durations are zero, d = valid (1s).
  if (total == 0) {
#pragma unroll
    for (int i = 0; i < 4; ++i) d[i] = (t0 + i < len) ? 1 : 0;
    s = d[0] + d[1] + d[2] + d[3];
  }

  // Inclusive wave scan of per-thread sums, then cross-wave offset.
  int v = s;
#pragma unroll
  for (int off = 1; off < 64; off <<= 1) {
    int u = __shfl_up(v, off);
    if (lane >= off) v += u;
  }
  if (lane == 63) wsum[wid] = v;
  __syncthreads();
  int wpre = 0;
#pragma unroll
  for (int w = 0; w < 4; ++w)
    if (w < wid) wpre += wsum[w];
  int run = wpre + v - s;  // exclusive prefix over this thread's 4 tokens

  // Scatter: token t owns frames [run, run + d[i]); intersect with window.
  const int flo = (int)f0, fhi = (int)f0 + FRAMES_PER_BLOCK;
#pragma unroll
  for (int i = 0; i < 4; ++i) {
    int lo = run, hi = run + d[i];
    run = hi;
    lo = lo < flo ? flo : lo;
    hi = hi > fhi ? fhi : hi;
    for (int k = lo; k < hi; ++k) map[k - flo] = t0 + i;
  }
  __syncthreads();

  // Streaming gather: 32 frames x 96 f4 = 3072 f4 = 256 threads x 12 iters.
  const f4* xrow = xs + (size_t)b * TT * F4_PER_ROW;
  f4* obase = out + ((size_t)b * T_OUT + f0) * F4_PER_ROW;
#pragma unroll
  for (int it = 0; it < G_ITERS; ++it) {
    const unsigned o = (unsigned)it * 256u + (unsigned)tid;
    const unsigned fl = o / F4_PER_ROW;          // frame within window
    const unsigned ln = o - fl * F4_PER_ROW;     // f4 within row
    const int src = map[fl];
    f4 val = {0.f, 0.f, 0.f, 0.f};
    if (src >= 0) val = xrow[(unsigned)src * F4_PER_ROW + ln];
    obase[o] = val;
  }
}

extern "C" void kernel_launch(void* const* d_in, const int* in_sizes, int n_in,
                              void* d_out, int out_size, void* d_ws, size_t ws_size,
                              hipStream_t stream) {
  const float* xs = (const float*)d_in[0];
  const int* durations = (const int*)d_in[1];
  const int* input_lengths = (const int*)d_in[2];
  float* out = (float*)d_out;

  lenreg_fused_kernel<<<BB * BLOCKS_PER_BATCH, 256, 0, stream>>>(
      (const f4*)xs, durations, input_lengths, (f4*)out);
}